// Round 4
// baseline (86.242 us; speedup 1.0000x reference)
//
#include <hip/hip_runtime.h>
#include <hip/hip_bf16.h>

// Problem: B=16, C=256, H=64, W=64, OUT=256
//   scale[b,c] = mean(context[b,c,:,:])
//   out[b,o,hw] = sum_c w1[o,c]*scale[b,c]*x[b,c,hw] + b1[o]
// R4: - scale folded into B during staging (w2 kernel eliminated)
//     - A = bf16(w1) fragments resident in registers (128 VGPR), loaded once
//     - 512 blocks x 4 col-tiles, double-buffered LDS (2x16KiB)
//     - raw s_barrier + manual lgkmcnt (no vmcnt drain -> prefetch overlaps)

typedef __attribute__((ext_vector_type(8))) short short8;
typedef __attribute__((ext_vector_type(4))) float f32x4;
typedef __attribute__((ext_vector_type(4))) unsigned int u32x4;

static __device__ __forceinline__ unsigned short f2bf(float f) {
    unsigned int u = __float_as_uint(f);
    unsigned int r = u + 0x7FFFu + ((u >> 16) & 1u);  // round-to-nearest-even
    return (unsigned short)(r >> 16);
}

static __device__ __forceinline__ unsigned int perm_b32(unsigned int a, unsigned int b,
                                                        unsigned int sel, int half) {
#if __has_builtin(__builtin_amdgcn_perm)
    (void)half;
    return __builtin_amdgcn_perm(a, b, sel);  // bytes: {a = hi src, b = lo src}
#else
    return half ? ((a & 0xffff0000u) | (b >> 16)) : ((a << 16) | (b & 0xffffu));
#endif
}

// ---------------- Kernel 1: scale[b*256+c] = mean over 4096 elems ----------
__global__ __launch_bounds__(256) void scale_kernel(const float* __restrict__ ctx,
                                                    float* __restrict__ scale) {
    const int bc = blockIdx.x;              // 0..4095
    const float4* p = (const float4*)(ctx + (size_t)bc * 4096);
    const int t = threadIdx.x;
    float s = 0.f;
#pragma unroll
    for (int k = 0; k < 4; k++) {
        float4 v = p[t + k * 256];
        s += v.x + v.y + v.z + v.w;
    }
#pragma unroll
    for (int off = 32; off > 0; off >>= 1) s += __shfl_down(s, off);
    __shared__ float ws[4];
    if ((t & 63) == 0) ws[t >> 6] = s;
    __syncthreads();
    if (t == 0) scale[bc] = (ws[0] + ws[1] + ws[2] + ws[3]) * (1.0f / 4096.0f);
}

// ---------------- Kernel 2: per-batch GEMM out = bf16(w1) * bf16(scale*x) + b1
// 512 blocks: b = bid>>5, col-group (bid&31)*128, 4 tiles of 32 cols each.
// 256 threads = 4 waves; wave w owns rows [64w,64w+64). A in registers.
// LDS (dword units): dw = k*16 + (cd ^ s(k)), cd=c>>1, s(k)=((k>>3)&1)<<3.
__global__ __launch_bounds__(256, 2) void gemm_kernel(const float* __restrict__ x,
                                                      const float* __restrict__ w1,
                                                      const float* __restrict__ scale,
                                                      const float* __restrict__ b1,
                                                      float* __restrict__ out) {
    __shared__ unsigned int xl[2][4096];  // 2 x (256 x 32 bf16, swizzled)

    const int bid = blockIdx.x;       // 512
    const int b = bid >> 5;           // batch
    const int col0 = (bid & 31) * 128;
    const int tid = threadIdx.x;
    const int w = tid >> 6;
    const int lane = tid & 63;
    const int g = lane >> 4;          // 0..3
    const int lr = lane & 15;         // 0..15
    const int o0 = w * 64;

    const float* Xb = x + (size_t)b * (256 * 4096);
    const float* scb = scale + b * 256;

    // ---- prologue: issue tile-0 staging loads first (HBM latency hides under A-cvt)
    const int krow = tid >> 3;        // 0..31
    const int cd = (tid & 7) * 2;     // even dword col 0..14
    float4 stg[8];
#pragma unroll
    for (int i = 0; i < 8; i++)
        stg[i] = *(const float4*)(Xb + (size_t)(krow + i * 32) * 4096 + col0 + cd * 2);

    // ---- A fragments into registers: A[ks][m], rows o0+m*16+lr, k=ks*32+g*8+e
    short8 A[8][4];
#pragma unroll
    for (int m = 0; m < 4; m++) {
        const float* wr = w1 + (o0 + m * 16 + lr) * 256;
#pragma unroll
        for (int ks = 0; ks < 8; ks++) {
            float4 p0 = *(const float4*)(wr + ks * 32 + g * 8);
            float4 p1 = *(const float4*)(wr + ks * 32 + g * 8 + 4);
            short8 v;
            v[0] = (short)f2bf(p0.x); v[1] = (short)f2bf(p0.y);
            v[2] = (short)f2bf(p0.z); v[3] = (short)f2bf(p0.w);
            v[4] = (short)f2bf(p1.x); v[5] = (short)f2bf(p1.y);
            v[6] = (short)f2bf(p1.z); v[7] = (short)f2bf(p1.w);
            A[ks][m] = v;
        }
    }

    // per-thread scale values for staging rows (same k's every tile)
    float sreg[8];
#pragma unroll
    for (int i = 0; i < 8; i++) sreg[i] = scb[krow + i * 32];

    // fragment-read constants
    const int half = lr & 1;
    const unsigned int sel = half ? 0x07060302u : 0x05040100u;
    int csw[2];
#pragma unroll
    for (int nt = 0; nt < 2; nt++)
        csw[nt] = ((nt * 16 + lr) >> 1) ^ ((g & 1) << 3);

    float* outb = out + (size_t)b * 256 * 4096;

#pragma unroll
    for (int t = 0; t < 4; t++) {
        const int hw0 = col0 + t * 32;
        unsigned int* buf = xl[t & 1];

        // ---- consume stg -> cvt(bf16, *scale) -> swizzled LDS writes
#pragma unroll
        for (int i = 0; i < 8; i++) {
            const int k = krow + i * 32;
            const float s = sreg[i];
            float4 v = stg[i];
            unsigned int lo = (unsigned int)f2bf(v.x * s) | ((unsigned int)f2bf(v.y * s) << 16);
            unsigned int hi = (unsigned int)f2bf(v.z * s) | ((unsigned int)f2bf(v.w * s) << 16);
            const int dw = k * 16 + (cd ^ (((k >> 3) & 1) << 3));
            *(uint2*)&buf[dw] = make_uint2(lo, hi);
        }

        // ---- issue next tile's loads (stay in flight across the raw barrier)
        if (t < 3) {
#pragma unroll
            for (int i = 0; i < 8; i++)
                stg[i] = *(const float4*)(Xb + (size_t)(krow + i * 32) * 4096 + hw0 + 32 + cd * 2);
        }

        // ---- LDS-write drain + raw barrier (no vmcnt(0) drain of prefetch)
        asm volatile("s_waitcnt lgkmcnt(0)" ::: "memory");
        __builtin_amdgcn_s_barrier();
        asm volatile("" ::: "memory");  // block hoisting ds_reads above barrier

        // ---- compute tile t
        f32x4 acc[4][2];
#pragma unroll
        for (int m = 0; m < 4; m++)
#pragma unroll
            for (int nt = 0; nt < 2; nt++) acc[m][nt] = (f32x4)(0.f);

#pragma unroll
        for (int ks = 0; ks < 8; ks++) {
#pragma unroll
            for (int nt = 0; nt < 2; nt++) {
                const int dwb = (ks * 32 + g * 8) * 16 + csw[nt];
                unsigned int d[8];
#pragma unroll
                for (int e = 0; e < 8; e++) d[e] = buf[dwb + e * 16];
                u32x4 pv;
#pragma unroll
                for (int j = 0; j < 4; j++) pv[j] = perm_b32(d[2 * j + 1], d[2 * j], sel, half);
                short8 bf = __builtin_bit_cast(short8, pv);
#pragma unroll
                for (int m = 0; m < 4; m++)
                    acc[m][nt] = __builtin_amdgcn_mfma_f32_16x16x32_bf16(A[ks][m], bf, acc[m][nt], 0, 0, 0);
            }
        }

        // ---- epilogue: D col = lane&15, row = 4*(lane>>4)+reg
#pragma unroll
        for (int m = 0; m < 4; m++) {
#pragma unroll
            for (int r = 0; r < 4; r++) {
                const int row = o0 + m * 16 + g * 4 + r;
                const float bias = b1[row];
#pragma unroll
                for (int nt = 0; nt < 2; nt++)
                    outb[(size_t)row * 4096 + hw0 + nt * 16 + lr] = acc[m][nt][r] + bias;
            }
        }
    }
}

extern "C" void kernel_launch(void* const* d_in, const int* in_sizes, int n_in,
                              void* d_out, int out_size, void* d_ws, size_t ws_size,
                              hipStream_t stream) {
    const float* x = (const float*)d_in[0];
    const float* context = (const float*)d_in[1];
    const float* w1 = (const float*)d_in[2];
    const float* b1 = (const float*)d_in[3];
    float* out = (float*)d_out;

    float* scale = (float*)d_ws;  // 4096 f32

    scale_kernel<<<4096, 256, 0, stream>>>(context, scale);
    gemm_kernel<<<512, 256, 0, stream>>>(x, w1, scale, b1, out);
}

// Round 6
// 51.521 us; speedup vs baseline: 1.6739x; 1.6739x over previous
//
#include <hip/hip_runtime.h>
#include <hip/hip_bf16.h>

// Problem: B=16, C=256, H=64, W=64, OUT=256
//   scale[b,c] = mean(context[b,c,:,:])
//   out[b,o,hw] = sum_c w1[o,c]*scale[b,c]*x[b,c,hw] + b1[o]
// R6: back to the proven no-LDS gemm (R1 structure, best real time so far) with
//     the two measured inefficiencies fixed:
//     - w2 pre-transposed to fragment-contiguous layout (A-loads fully coalesced,
//       kills 4x L2 over-traffic of 16B@512B-stride loads)
//     - waves split columns (no 4x redundant B-reads); B dbuf 1-ks ahead
//     2048 blocks, __launch_bounds__(256,4) -> exactly 2 residency waves.

typedef __attribute__((ext_vector_type(8))) short short8;
typedef __attribute__((ext_vector_type(4))) float f32x4;
typedef __attribute__((ext_vector_type(4))) unsigned int u32x4;

static __device__ __forceinline__ unsigned int bfbits(float f) {
    unsigned int u = __float_as_uint(f);
    return u + 0x7FFFu + ((u >> 16) & 1u);  // bf16 (RTNE) in bits 16..31
}

// dword = bf16(lo) | bf16(hi)<<16
static __device__ __forceinline__ unsigned int pkbf(float lo, float hi) {
#if __has_builtin(__builtin_amdgcn_perm)
    return __builtin_amdgcn_perm(bfbits(hi), bfbits(lo), 0x07060302u);
#else
    return (bfbits(lo) >> 16) | (bfbits(hi) & 0xffff0000u);
#endif
}

// ---------------- Kernel 1: scale[b*256+c] = mean over 4096 elems ----------
__global__ __launch_bounds__(256) void scale_kernel(const float* __restrict__ ctx,
                                                    float* __restrict__ scale) {
    const int bc = blockIdx.x;              // 0..4095
    const float4* p = (const float4*)(ctx + (size_t)bc * 4096);
    const int t = threadIdx.x;
    float s = 0.f;
#pragma unroll
    for (int k = 0; k < 4; k++) {
        float4 v = p[t + k * 256];
        s += v.x + v.y + v.z + v.w;
    }
#pragma unroll
    for (int off = 32; off > 0; off >>= 1) s += __shfl_down(s, off);
    __shared__ float ws[4];
    if ((t & 63) == 0) ws[t >> 6] = s;
    __syncthreads();
    if (t == 0) scale[bc] = (ws[0] + ws[1] + ws[2] + ws[3]) * (1.0f / 4096.0f);
}

// ---------------- Kernel 2: w2f = scale-folded w1, fragment-contiguous ------
// w2f element layout (ushort units): [((b*8+ks)*16 + m16)*64 + lane]*8 + e
//   = bf16( w1[m16*16 + (lane&15)][ks*32 + (lane>>4)*8 + e] * scale[b][same c] )
// One thread per 8-elem fragment row: gt = b*8192 + ks*1024 + m16*64 + lane.
__global__ __launch_bounds__(256) void w2f_kernel(const float* __restrict__ w1,
                                                  const float* __restrict__ scale,
                                                  unsigned short* __restrict__ w2f) {
    const int gt = blockIdx.x * 256 + threadIdx.x;  // 0..131071
    const int lane = gt & 63;
    const int m16 = (gt >> 6) & 15;
    const int ks = (gt >> 10) & 7;
    const int b = gt >> 13;
    const int lr = lane & 15;
    const int g = lane >> 4;
    const int row = m16 * 16 + lr;
    const int c0 = ks * 32 + g * 8;

    const float* wr = w1 + row * 256 + c0;
    const float* sc = scale + b * 256 + c0;
    float4 wv0 = *(const float4*)(wr);
    float4 wv1 = *(const float4*)(wr + 4);
    float4 sv0 = *(const float4*)(sc);
    float4 sv1 = *(const float4*)(sc + 4);

    u32x4 pv;
    pv[0] = pkbf(wv0.x * sv0.x, wv0.y * sv0.y);
    pv[1] = pkbf(wv0.z * sv0.z, wv0.w * sv0.w);
    pv[2] = pkbf(wv1.x * sv1.x, wv1.y * sv1.y);
    pv[3] = pkbf(wv1.z * sv1.z, wv1.w * sv1.w);
    *(u32x4*)(w2f + (size_t)gt * 8) = pv;   // coalesced 16B store
}

// ---------------- Kernel 3: per-batch GEMM out = A(w2f) * bf16(x) + b1 ------
// 2048 blocks: b = bid>>7, col tile (bid&127)*32. 4 waves:
//   wave w: rows (w&1)*128..+128, cols +(w>>1)*16. acc[8] (32 VGPR).
// No LDS, no barriers. A coalesced short8 from w2f; B scalar f32 (stride 4096)
// double-buffered one ks ahead; pack via bfbits+v_perm.
__global__ __launch_bounds__(256, 4) void gemm_kernel(const float* __restrict__ x,
                                                      const unsigned short* __restrict__ w2f,
                                                      const float* __restrict__ b1,
                                                      float* __restrict__ out) {
    const int bid = blockIdx.x;        // 2048
    const int b = bid >> 7;            // batch
    const int hw0 = (bid & 127) * 32;  // 32-col tile
    const int tid = threadIdx.x;
    const int w = tid >> 6;
    const int lane = tid & 63;
    const int g = lane >> 4;
    const int lr = lane & 15;
    const int o0 = (w & 1) * 128;            // row half
    const int cw = hw0 + (w >> 1) * 16;      // wave's 16-col group
    const int m16b = (w & 1) * 8;            // row-half in m16 units

    const unsigned short* Af = w2f + (size_t)b * 65536;   // [8ks][16m16][64lane][8]
    const float* Xcol = x + (size_t)b * (256 * 4096) + cw + lr;  // per-lane column

    f32x4 acc[8];
#pragma unroll
    for (int m = 0; m < 8; m++) acc[m] = (f32x4)(0.f);

    float bcur[8], bnxt[8];
#pragma unroll
    for (int e = 0; e < 8; e++) bcur[e] = Xcol[(size_t)(g * 8 + e) * 4096];

#pragma unroll
    for (int ks = 0; ks < 8; ks++) {
        // issue next-ks B loads first (HBM/L3 latency hides under this ks)
        if (ks < 7) {
#pragma unroll
            for (int e = 0; e < 8; e++)
                bnxt[e] = Xcol[(size_t)((ks + 1) * 32 + g * 8 + e) * 4096];
        }
        // A fragments: fully coalesced 16B/lane from L2-resident w2f
        short8 a[8];
#pragma unroll
        for (int m = 0; m < 8; m++)
            a[m] = *(const short8*)(Af + ((size_t)(ks * 16 + m16b + m) * 64 + lane) * 8);
        // pack B to bf16x8
        u32x4 pv;
#pragma unroll
        for (int j = 0; j < 4; j++) pv[j] = pkbf(bcur[2 * j], bcur[2 * j + 1]);
        short8 bf = __builtin_bit_cast(short8, pv);
#pragma unroll
        for (int m = 0; m < 8; m++)
            acc[m] = __builtin_amdgcn_mfma_f32_16x16x32_bf16(a[m], bf, acc[m], 0, 0, 0);
#pragma unroll
        for (int e = 0; e < 8; e++) bcur[e] = bnxt[e];
    }

    // epilogue: D col = lane&15 (cw+lr), row = o0 + m*16 + g*4 + r
    float* outp = out + (size_t)b * 256 * 4096 + cw + lr;
#pragma unroll
    for (int m = 0; m < 8; m++) {
#pragma unroll
        for (int r = 0; r < 4; r++) {
            const int row = o0 + m * 16 + g * 4 + r;
            outp[(size_t)row * 4096] = acc[m][r] + b1[row];
        }
    }
}

extern "C" void kernel_launch(void* const* d_in, const int* in_sizes, int n_in,
                              void* d_out, int out_size, void* d_ws, size_t ws_size,
                              hipStream_t stream) {
    const float* x = (const float*)d_in[0];
    const float* context = (const float*)d_in[1];
    const float* w1 = (const float*)d_in[2];
    const float* b1 = (const float*)d_in[3];
    float* out = (float*)d_out;

    float* scale = (float*)d_ws;                                   // 16 KB
    unsigned short* w2f = (unsigned short*)((char*)d_ws + 16384);  // 2 MB

    scale_kernel<<<4096, 256, 0, stream>>>(context, scale);
    w2f_kernel<<<512, 256, 0, stream>>>(w1, scale, w2f);
    gemm_kernel<<<2048, 256, 0, stream>>>(x, w2f, b1, out);
}

// Round 7
// 42.486 us; speedup vs baseline: 2.0299x; 1.2127x over previous
//
#include <hip/hip_runtime.h>
#include <hip/hip_bf16.h>

// Problem: B=16, C=256, H=64, W=64, OUT=256
//   scale[b,c] = mean(context[b,c,:,:])
//   out[b,o,hw] = sum_c w1[o,c]*scale[b,c]*x[b,c,hw] + b1[o]
// R7: m97-style staging: B-tile (f32, linear) -> LDS via global_load_lds
//     dwordx4, double-buffered, one barrier per BK step (min-2-phase T3-lite).
//     MFMA 32x32x16 (B-frag col=lane&31 -> LDS reads 32-bank 2-way = free).
//     A = scale-folded bf16 w2f in fragment-contiguous layout, batch-prefetched.

typedef __attribute__((ext_vector_type(8))) short short8;
typedef __attribute__((ext_vector_type(16))) float f32x16;
typedef __attribute__((ext_vector_type(4))) unsigned int u32x4;

static __device__ __forceinline__ unsigned int bfbits(float f) {
    unsigned int u = __float_as_uint(f);
    return u + 0x7FFFu + ((u >> 16) & 1u);  // bf16 (RTNE) in bits 16..31
}

// dword = bf16(lo) | bf16(hi)<<16
static __device__ __forceinline__ unsigned int pkbf(float lo, float hi) {
#if __has_builtin(__builtin_amdgcn_perm)
    return __builtin_amdgcn_perm(bfbits(hi), bfbits(lo), 0x07060302u);
#else
    return (bfbits(lo) >> 16) | (bfbits(hi) & 0xffff0000u);
#endif
}

// async global->LDS, 16B per lane (linear LDS dest: wave base + lane*16)
static __device__ __forceinline__ void gload16(const void* g, void* l) {
    __builtin_amdgcn_global_load_lds(
        (const __attribute__((address_space(1))) unsigned int*)g,
        (__attribute__((address_space(3))) unsigned int*)l, 16, 0, 0);
}

// ---------------- Kernel 1: scale[b*256+c] = mean over 4096 elems ----------
__global__ __launch_bounds__(256) void scale_kernel(const float* __restrict__ ctx,
                                                    float* __restrict__ scale) {
    const int bc = blockIdx.x;              // 0..4095
    const float4* p = (const float4*)(ctx + (size_t)bc * 4096);
    const int t = threadIdx.x;
    float s = 0.f;
#pragma unroll
    for (int k = 0; k < 4; k++) {
        float4 v = p[t + k * 256];
        s += v.x + v.y + v.z + v.w;
    }
#pragma unroll
    for (int off = 32; off > 0; off >>= 1) s += __shfl_down(s, off);
    __shared__ float ws[4];
    if ((t & 63) == 0) ws[t >> 6] = s;
    __syncthreads();
    if (t == 0) scale[bc] = (ws[0] + ws[1] + ws[2] + ws[3]) * (1.0f / 4096.0f);
}

// ---------------- Kernel 2: w2f = scale-folded w1, 32x32x16-fragment layout -
// w2f (ushort): [((b*16+ks)*8 + mt)*64 + lane]*8 + e
//   = bf16( w1[mt*32+(lane&31)][ks*16+(lane>>5)*8+e] * scale[b][same c] )
__global__ __launch_bounds__(256) void w2f_kernel(const float* __restrict__ w1,
                                                  const float* __restrict__ scale,
                                                  unsigned short* __restrict__ w2f) {
    const int gt = blockIdx.x * 256 + threadIdx.x;  // 0..131071
    const int l = gt & 63;
    const int mt = (gt >> 6) & 7;
    const int ks = (gt >> 9) & 15;
    const int b = gt >> 13;
    const int row = mt * 32 + (l & 31);
    const int c0 = ks * 16 + (l >> 5) * 8;

    const float* wr = w1 + row * 256 + c0;
    const float* sc = scale + b * 256 + c0;
    float4 wv0 = *(const float4*)(wr);
    float4 wv1 = *(const float4*)(wr + 4);
    float4 sv0 = *(const float4*)(sc);
    float4 sv1 = *(const float4*)(sc + 4);

    u32x4 pv;
    pv[0] = pkbf(wv0.x * sv0.x, wv0.y * sv0.y);
    pv[1] = pkbf(wv0.z * sv0.z, wv0.w * sv0.w);
    pv[2] = pkbf(wv1.x * sv1.x, wv1.y * sv1.y);
    pv[3] = pkbf(wv1.z * sv1.z, wv1.w * sv1.w);
    *(u32x4*)(w2f + (size_t)gt * 8) = pv;   // coalesced 16B store
}

// ---------------- Kernel 3: per-batch GEMM out = A(w2f) * bf16(x) + b1 ------
// 1024 blocks: b = bid>>6, col tile (bid&63)*64. 4 waves; wave w = rows [64w,+64)
// as 2x2 MFMA-32x32 tiles over 64 cols. B staged f32 [64k][64c] in LDS (dbuf).
__global__ __launch_bounds__(256, 3) void gemm_kernel(const float* __restrict__ x,
                                                      const unsigned short* __restrict__ w2f,
                                                      const float* __restrict__ b1,
                                                      float* __restrict__ out) {
    __shared__ float bst[2][4096];     // 2 x (64k x 64c f32) = 32 KiB

    const int bid = blockIdx.x;        // 1024
    const int b = bid >> 6;
    const int hw0 = (bid & 63) * 64;
    const int tid = threadIdx.x;
    const int w = tid >> 6;
    const int lane = tid & 63;
    const int l31 = lane & 31;
    const int lh = lane >> 5;          // 0/1
    const int o0 = w * 64;

    const unsigned short* Af = w2f + (size_t)b * 65536;   // [16ks][8mt][64l][8]
    const float* Xb = x + (size_t)b * (256 * 4096) + hw0;

    // ---- prologue: stage kt=0 tile (4 x 16B per thread, linear LDS)
#pragma unroll
    for (int i = 0; i < 4; i++) {
        const int idx = i * 256 + tid;              // granule 0..1023
        gload16(Xb + (size_t)(idx >> 4) * 4096 + (idx & 15) * 4, &bst[0][idx * 4]);
    }
    __syncthreads();

    f32x16 acc[2][2];
#pragma unroll
    for (int mtl = 0; mtl < 2; mtl++)
#pragma unroll
        for (int ntl = 0; ntl < 2; ntl++) acc[mtl][ntl] = (f32x16)(0.f);

    const int bbase = lh * 512 + l31;  // dword idx; + ntl*32 + sub*1024 + e*64

#pragma unroll
    for (int kt = 0; kt < 4; kt++) {
        // ---- issue next tile's staging (in flight across this kt's compute)
        if (kt < 3) {
#pragma unroll
            for (int i = 0; i < 4; i++) {
                const int idx = i * 256 + tid;
                gload16(Xb + (size_t)((kt + 1) * 64 + (idx >> 4)) * 4096 + (idx & 15) * 4,
                        &bst[(kt + 1) & 1][idx * 4]);
            }
        }
        const float* bb = bst[kt & 1];

        // ---- batch A prefetch: 8 frags, all in flight together (L2-hot)
        short8 a[4][2];
#pragma unroll
        for (int sub = 0; sub < 4; sub++)
#pragma unroll
            for (int mtl = 0; mtl < 2; mtl++)
                a[sub][mtl] = *(const short8*)(
                    Af + (((size_t)(kt * 4 + sub) * 8 + (w * 2 + mtl)) * 64 + lane) * 8);

        // ---- compute: per sub-K16: 2 B-frags (8 ds_read each, 2-way = free) + 4 MFMA
#pragma unroll
        for (int sub = 0; sub < 4; sub++) {
#pragma unroll
            for (int ntl = 0; ntl < 2; ntl++) {
                float bf32[8];
#pragma unroll
                for (int e = 0; e < 8; e++)
                    bf32[e] = bb[bbase + ntl * 32 + sub * 1024 + e * 64];
                u32x4 pv;
#pragma unroll
                for (int j = 0; j < 4; j++) pv[j] = pkbf(bf32[2 * j], bf32[2 * j + 1]);
                short8 bfr = __builtin_bit_cast(short8, pv);
#pragma unroll
                for (int mtl = 0; mtl < 2; mtl++)
                    acc[mtl][ntl] = __builtin_amdgcn_mfma_f32_32x32x16_bf16(
                        a[sub][mtl], bfr, acc[mtl][ntl], 0, 0, 0);
            }
        }
        __syncthreads();  // drains next-stage vmcnt + this kt's lgkm; 1 barrier/kt
    }

    // ---- epilogue: D (32x32): col = lane&31, row = (r&3) + 8*(r>>2) + 4*lh
    float* outb = out + (size_t)b * 256 * 4096 + hw0;
#pragma unroll
    for (int mtl = 0; mtl < 2; mtl++)
#pragma unroll
        for (int ntl = 0; ntl < 2; ntl++)
#pragma unroll
            for (int r = 0; r < 16; r++) {
                const int row = o0 + mtl * 32 + (r & 3) + 8 * (r >> 2) + 4 * lh;
                outb[(size_t)row * 4096 + ntl * 32 + l31] = acc[mtl][ntl][r] + b1[row];
            }
}

extern "C" void kernel_launch(void* const* d_in, const int* in_sizes, int n_in,
                              void* d_out, int out_size, void* d_ws, size_t ws_size,
                              hipStream_t stream) {
    const float* x = (const float*)d_in[0];
    const float* context = (const float*)d_in[1];
    const float* w1 = (const float*)d_in[2];
    const float* b1 = (const float*)d_in[3];
    float* out = (float*)d_out;

    float* scale = (float*)d_ws;                                   // 16 KB
    unsigned short* w2f = (unsigned short*)((char*)d_ws + 16384);  // 2 MB

    scale_kernel<<<4096, 256, 0, stream>>>(context, scale);
    w2f_kernel<<<512, 256, 0, stream>>>(w1, scale, w2f);
    gemm_kernel<<<1024, 256, 0, stream>>>(x, w2f, b1, out);
}